// Round 1
// baseline (1393.525 us; speedup 1.0000x reference)
//
#include <hip/hip_runtime.h>

#define FF 512
#define LL 12288
#define LP 12352   // LL + 64 zero pad (causal mask + k-step overrun)
#define NBATCH 8

typedef _Float16 half8 __attribute__((ext_vector_type(8)));
typedef float    f32x4 __attribute__((ext_vector_type(4)));

// ---------------- Prologue 1: kernel fp32 -> f16, MFMA-A-fragment tiled ----
// At unit = 16B chunk per (ft16, dc32, lane): value_i = kernel[ft*16 + (lane&15)][dc*32 + (lane>>4)*8 + i]
__global__ __launch_bounds__(256) void build_At(const float* __restrict__ kern,
                                                _Float16* __restrict__ At) {
    int tid  = blockIdx.x * 256 + threadIdx.x;      // 786432 total = 512*12288/8
    int lane = tid & 63;
    int rest = tid >> 6;                            // ft*384 + dc
    int dc   = rest % 384;
    int ft   = rest / 384;
    int f    = ft * 16 + (lane & 15);
    int d0   = dc * 32 + (lane >> 4) * 8;
    const float* src = kern + (size_t)f * LL + d0;
    half8 v;
#pragma unroll
    for (int i = 0; i < 8; ++i) v[i] = (_Float16)src[i];
    ((half8*)At)[tid] = v;
}

// ---------------- Prologue 2: reversed, shifted, zero-padded x copies ------
// XR[s][b][j] = x_b[L-1-j-s] for j <= L-1-s else 0 ;  x = example*0.5 - 1
__global__ __launch_bounds__(256) void build_XR(const int* __restrict__ ex,
                                                _Float16* __restrict__ XR) {
    int tid = blockIdx.x * 256 + threadIdx.x;       // 790528 total = 8*8*LP
    int j    = tid % LP;
    int rest = tid / LP;                            // s*8 + b
    int b    = rest & 7;
    int s    = rest >> 3;
    int src  = LL - 1 - j - s;
    float v = 0.f;
    if (src >= 0) v = (float)ex[b * LL + src] * 0.5f - 1.0f;
    XR[tid] = (_Float16)v;
}

// ---------------- Prologue 3: out = dense_b broadcast ----------------------
__global__ __launch_bounds__(256) void init_out(const float* __restrict__ db,
                                                float* __restrict__ out) {
    int tid = blockIdx.x * 256 + threadIdx.x;       // 393216 total
    out[tid] = db[tid & 3];
}

// ---------------- Main: causal-Toeplitz GEMM + fused relu/dense epilogue ---
// Block: 256 thr = 4 waves (2x2). Block tile M=128 f-rows x N=128 cols
// (cols = 8 batches x 16 n-positions). Wave tile 64x64 = 4x4 mfma 16x16x32.
// Col-tile t in [0,8): col j: b=j&7, nh=j>>3, n = n0 + t + 8*nh.
// B frag from XR[s=7-t]: contiguous 16B-aligned, causal zeros via pad.
__global__ __launch_bounds__(256) void conv_main(const _Float16* __restrict__ At,
                                                 const _Float16* __restrict__ XR,
                                                 const float* __restrict__ bias,
                                                 const float* __restrict__ dw,
                                                 float* __restrict__ out) {
    int bx   = blockIdx.x;
    int slot = bx & 7;                    // XCD slot: pin f_blk to XCD pairs for L2 reuse
    int f_blk = slot >> 1;                // [0,4)
    int n_blk = (bx >> 3) * 2 + (slot & 1);
    n_blk = 767 - n_blk;                  // largest K first -> small scheduling tail
    int n0 = n_blk << 4;
    int S  = (n0 + 47) >> 5;              // ceil((n0+16)/32) K32-steps, >= 1

    int tid  = threadIdx.x;
    int lane = tid & 63;
    int wid  = tid >> 6;
    int wave_m = wid >> 1, wave_n = wid & 1;
    int quad = lane >> 4;
    int bb   = lane & 7;
    int nh   = (lane >> 3) & 1;

    // A fragment pointers (per row-tile), unit = half8 (16B)
    const half8* pA[4];
#pragma unroll
    for (int r = 0; r < 4; ++r) {
        int ft = f_blk * 8 + wave_m * 4 + r;              // 16-row tile idx [0,32)
        pA[r] = (const half8*)At + ((size_t)ft * 384) * 64 + lane;
    }
    // B fragment pointers (per col-tile). J0 independent of t; s_t = 7 - t.
    int J0 = (LL - 8 - n0) + 8 * (quad - nh);             // multiple of 8 -> 16B aligned
    const half8* pB[4];
#pragma unroll
    for (int t = 0; t < 4; ++t) {
        int tt = wave_n * 4 + t;
        int s  = 7 - tt;
        pB[t] = (const half8*)(XR + (size_t)(s * 8 + bb) * LP + J0);
    }

    f32x4 acc[4][4];
#pragma unroll
    for (int r = 0; r < 4; ++r)
#pragma unroll
        for (int t = 0; t < 4; ++t) acc[r][t] = (f32x4){0.f, 0.f, 0.f, 0.f};

    half8 a[4], bf[4];
#pragma unroll
    for (int r = 0; r < 4; ++r) a[r] = pA[r][0];
#pragma unroll
    for (int t = 0; t < 4; ++t) bf[t] = pB[t][0];

    // K loop: 1-deep software pipeline, no LDS, no barriers.
    for (int dc = 1; dc < S; ++dc) {
        half8 a2[4], b2[4];
#pragma unroll
        for (int r = 0; r < 4; ++r) a2[r] = pA[r][(size_t)dc * 64];  // +1KB/step
#pragma unroll
        for (int t = 0; t < 4; ++t) b2[t] = pB[t][(size_t)dc * 4];   // +32 elems/step
#pragma unroll
        for (int r = 0; r < 4; ++r)
#pragma unroll
            for (int t = 0; t < 4; ++t)
                acc[r][t] = __builtin_amdgcn_mfma_f32_16x16x32_f16(a[r], bf[t], acc[r][t], 0, 0, 0);
#pragma unroll
        for (int r = 0; r < 4; ++r) a[r] = a2[r];
#pragma unroll
        for (int t = 0; t < 4; ++t) bf[t] = b2[t];
    }
#pragma unroll
    for (int r = 0; r < 4; ++r)
#pragma unroll
        for (int t = 0; t < 4; ++t)
            acc[r][t] = __builtin_amdgcn_mfma_f32_16x16x32_f16(a[r], bf[t], acc[r][t], 0, 0, 0);

    // Epilogue: bias + relu + dense partial over this block's 128 f rows.
    // C/D layout: col = lane&15, row = quad*4 + reg.
    float p[4][4] = {{0.f}};
#pragma unroll
    for (int r = 0; r < 4; ++r) {
#pragma unroll
        for (int reg = 0; reg < 4; ++reg) {
            int f = f_blk * 128 + (wave_m * 4 + r) * 16 + quad * 4 + reg;
            float bs = bias[f];
            float4 w = *(const float4*)(dw + (size_t)f * 4);
#pragma unroll
            for (int t = 0; t < 4; ++t) {
                float y = acc[r][t][reg] + bs;
                y = fmaxf(y, 0.f);
                p[t][0] += y * w.x; p[t][1] += y * w.y;
                p[t][2] += y * w.z; p[t][3] += y * w.w;
            }
        }
    }
    // reduce the 4 quads (same col, different f rows)
#pragma unroll
    for (int t = 0; t < 4; ++t)
#pragma unroll
        for (int c = 0; c < 4; ++c) {
            float v = p[t][c];
            v += __shfl_xor(v, 16, 64);
            v += __shfl_xor(v, 32, 64);
            p[t][c] = v;
        }
    if (quad == 0) {
#pragma unroll
        for (int t = 0; t < 4; ++t) {
            int tt = wave_n * 4 + t;
            int n  = n0 + tt + 8 * nh;
            float* o = out + ((size_t)bb * LL + n) * 4;
#pragma unroll
            for (int c = 0; c < 4; ++c) atomicAdd(o + c, p[t][c]);
        }
    }
}

extern "C" void kernel_launch(void* const* d_in, const int* in_sizes, int n_in,
                              void* d_out, int out_size, void* d_ws, size_t ws_size,
                              hipStream_t stream) {
    const int*   ex   = (const int*)d_in[0];     // example  [8,64,64,3] int32
    const float* kern = (const float*)d_in[1];   // kernel   [512,12288]
    const float* bias = (const float*)d_in[2];   // bias     [512]
    const float* dw   = (const float*)d_in[3];   // dense_w  [512,4]
    const float* db   = (const float*)d_in[4];   // dense_b  [4]
    float* out = (float*)d_out;                  // [8,64,64,3,4] fp32

    _Float16* At = (_Float16*)d_ws;                                    // 12.58 MB
    _Float16* XR = (_Float16*)((char*)d_ws + (size_t)FF * LL * 2);     // 1.58 MB

    hipLaunchKernelGGL(build_At, dim3(3072), dim3(256), 0, stream, kern, At);
    hipLaunchKernelGGL(build_XR, dim3(3088), dim3(256), 0, stream, ex, XR);
    hipLaunchKernelGGL(init_out, dim3(1536), dim3(256), 0, stream, db, out);
    hipLaunchKernelGGL(conv_main, dim3(3072), dim3(256), 0, stream, At, XR, bias, dw, out);
}

// Round 2
// 583.282 us; speedup vs baseline: 2.3891x; 2.3891x over previous
//
#include <hip/hip_runtime.h>

#define FF 512
#define LL 12288
#define NJC 1544   // XB chunk count: need ceil((LL+40)/8)=1541, padded
#define NR 128     // XB rows = 16 shifts x 8 batches

typedef _Float16 half8 __attribute__((ext_vector_type(8)));
typedef float    f32x4 __attribute__((ext_vector_type(4)));

// ---------------- Prologue 1: kernel fp32 -> f16, MFMA-A-fragment tiled ----
// At chunk (ft,dc,lane): elem_i = kernel[ft*16 + (lane&15)][dc*32 + (lane>>4)*8 + i]
__global__ __launch_bounds__(256) void build_At(const float* __restrict__ kern,
                                                _Float16* __restrict__ At) {
    int tid  = blockIdx.x * 256 + threadIdx.x;      // 786432 = 512*12288/8
    int lane = tid & 63;
    int rest = tid >> 6;                            // ft*384 + dc
    int dc   = rest % 384;
    int ft   = rest / 384;
    int f    = ft * 16 + (lane & 15);
    int d0   = dc * 32 + (lane >> 4) * 8;
    const float* src = kern + (size_t)f * LL + d0;
    half8 v;
#pragma unroll
    for (int i = 0; i < 8; ++i) v[i] = (_Float16)src[i];
    ((half8*)At)[tid] = v;
}

// ---------------- Prologue 2: B chunk-major layout --------------------------
// XB[jc][r] (16B chunks): r = s*8 + b, s in [0,16). elem_i = x_b[LL-1-(8jc+i)-s]
// (zero when index < 0 -> causal mask for free). x = example*0.5 - 1.
__global__ __launch_bounds__(256) void build_XB(const int* __restrict__ ex,
                                                _Float16* __restrict__ XB) {
    int tid = blockIdx.x * 256 + threadIdx.x;       // 197632 = NJC*NR
    int r  = tid & 127;
    int jc = tid >> 7;
    int s  = r >> 3, b = r & 7;
    int j0 = jc * 8;
    half8 v;
#pragma unroll
    for (int i = 0; i < 8; ++i) {
        int idx = LL - 1 - (j0 + i) - s;
        float x = 0.f;
        if (idx >= 0) x = (float)ex[b * LL + idx] * 0.5f - 1.0f;
        v[i] = (_Float16)x;
    }
    ((half8*)XB)[tid] = v;
}

// ---------------- Prologue 3: out = dense_b broadcast ----------------------
__global__ __launch_bounds__(256) void init_out(const float* __restrict__ db,
                                                float* __restrict__ out) {
    int tid = blockIdx.x * 256 + threadIdx.x;       // 393216
    out[tid] = db[tid & 3];
}

__device__ __forceinline__ void gl_lds16(const half8* g, half8* l) {
    __builtin_amdgcn_global_load_lds((const __attribute__((address_space(1))) void*)g,
                                     (__attribute__((address_space(3))) void*)l, 16, 0, 0);
}

// ---------------- Main: A via LDS (shared), B register-direct --------------
// Block 128f x 256cols, 4 waves, wave tile 128x64 (8x4 mfma 16x16x32 f16).
// Cols: n = n0 + tt + 16*nh, b = bb; tt = wid*4 + t in [0,16); shift s = 15-tt.
// B frag: XB chunk jc = (1534 - 4*n_blk) + 4*dc + quad - 2*nh, row (15-tt)*8+bb.
__global__ __launch_bounds__(256, 2) void conv_main(const _Float16* __restrict__ At,
                                                    const _Float16* __restrict__ XB,
                                                    const float* __restrict__ bias,
                                                    const float* __restrict__ dw,
                                                    float* __restrict__ out) {
    __shared__ half8 Abuf[2][8][64];   // 16 KB double-buffered A tile (128f x 32k)

    int bx    = blockIdx.x;
    int slot  = bx & 7;                // XCD pin: f_blk per XCD pair for L2 reuse
    int f_blk = slot >> 1;             // [0,4)
    int n_blk = 383 - ((bx >> 3) * 2 + (slot & 1));   // largest K first
    int n0 = n_blk << 5;
    int S  = n_blk + 1;                // K32-steps

    int tid  = threadIdx.x;
    int lane = tid & 63;
    int wid  = tid >> 6;               // wave_n in [0,4)
    int quad = lane >> 4;
    int bb   = lane & 7;
    int nh   = (lane >> 3) & 1;

    // A staging: wave wid stages ft = wid and wid+4; contiguous 1KB per load.
    const half8* Ag = (const half8*)At;
    const half8* ag0 = Ag + ((size_t)(f_blk * 8 + wid) * 384) * 64 + lane;
    const half8* ag1 = Ag + ((size_t)(f_blk * 8 + wid + 4) * 384) * 64 + lane;

    // B pointers (half8 units): idx = jc*128 + r; step advance = 4*128 = 512.
    const half8* Bg = (const half8*)XB;
    int jc0 = 1534 - 4 * n_blk + quad - 2 * nh;
    const half8* pB[4];
#pragma unroll
    for (int t = 0; t < 4; ++t) {
        int tt = wid * 4 + t;
        int r  = (15 - tt) * 8 + bb;
        pB[t] = Bg + (size_t)jc0 * 128 + r;
    }

    f32x4 acc[8][4];
#pragma unroll
    for (int r8 = 0; r8 < 8; ++r8)
#pragma unroll
        for (int t = 0; t < 4; ++t) acc[r8][t] = (f32x4){0.f, 0.f, 0.f, 0.f};

    // pipeline prologue: stage A(0) -> buf0, load B(0)
    gl_lds16(ag0, &Abuf[0][wid][lane]);
    gl_lds16(ag1, &Abuf[0][wid + 4][lane]);
    half8 bcur[4], bnxt[4];
#pragma unroll
    for (int t = 0; t < 4; ++t) bcur[t] = pB[t][0];
    __syncthreads();

    for (int dc = 0; dc < S; ++dc) {
        int buf = dc & 1;
        bool more = (dc + 1 < S);
        if (more) {
            size_t oa = (size_t)(dc + 1) * 64;
            gl_lds16(ag0 + oa, &Abuf[buf ^ 1][wid][lane]);
            gl_lds16(ag1 + oa, &Abuf[buf ^ 1][wid + 4][lane]);
            size_t ob = (size_t)(dc + 1) * 512;
#pragma unroll
            for (int t = 0; t < 4; ++t) bnxt[t] = pB[t][ob];
        }
        half8 a[8];
#pragma unroll
        for (int r8 = 0; r8 < 8; ++r8) a[r8] = Abuf[buf][r8][lane];
#pragma unroll
        for (int r8 = 0; r8 < 8; ++r8)
#pragma unroll
            for (int t = 0; t < 4; ++t)
                acc[r8][t] = __builtin_amdgcn_mfma_f32_16x16x32_f16(a[r8], bcur[t], acc[r8][t], 0, 0, 0);
        __syncthreads();
        if (more) {
#pragma unroll
            for (int t = 0; t < 4; ++t) bcur[t] = bnxt[t];
        }
    }

    // Epilogue: bias + relu + dense over this block's 128 f rows.
    // C/D layout: col = lane&15, row = quad*4 + reg.
    float p[4][4] = {{0.f}};
#pragma unroll
    for (int r8 = 0; r8 < 8; ++r8) {
#pragma unroll
        for (int reg = 0; reg < 4; ++reg) {
            int f = f_blk * 128 + r8 * 16 + quad * 4 + reg;
            float bs = bias[f];
            float4 w = *(const float4*)(dw + (size_t)f * 4);
#pragma unroll
            for (int t = 0; t < 4; ++t) {
                float y = fmaxf(acc[r8][t][reg] + bs, 0.f);
                p[t][0] += y * w.x; p[t][1] += y * w.y;
                p[t][2] += y * w.z; p[t][3] += y * w.w;
            }
        }
    }
#pragma unroll
    for (int t = 0; t < 4; ++t)
#pragma unroll
        for (int c = 0; c < 4; ++c) {
            float v = p[t][c];
            v += __shfl_xor(v, 16, 64);
            v += __shfl_xor(v, 32, 64);
            p[t][c] = v;
        }
    if (quad == 0) {
#pragma unroll
        for (int t = 0; t < 4; ++t) {
            int n = n0 + (wid * 4 + t) + 16 * nh;
            float* o = out + ((size_t)bb * LL + n) * 4;
#pragma unroll
            for (int c = 0; c < 4; ++c) atomicAdd(o + c, p[t][c]);
        }
    }
}

extern "C" void kernel_launch(void* const* d_in, const int* in_sizes, int n_in,
                              void* d_out, int out_size, void* d_ws, size_t ws_size,
                              hipStream_t stream) {
    const int*   ex   = (const int*)d_in[0];
    const float* kern = (const float*)d_in[1];
    const float* bias = (const float*)d_in[2];
    const float* dw   = (const float*)d_in[3];
    const float* db   = (const float*)d_in[4];
    float* out = (float*)d_out;

    _Float16* At = (_Float16*)d_ws;                                   // 12.58 MB
    _Float16* XB = (_Float16*)((char*)d_ws + (size_t)FF * LL * 2);    // +3.16 MB = 15.75 MB total

    hipLaunchKernelGGL(build_At, dim3(3072), dim3(256), 0, stream, kern, At);
    hipLaunchKernelGGL(build_XB, dim3(772),  dim3(256), 0, stream, ex, XB);
    hipLaunchKernelGGL(init_out, dim3(1536), dim3(256), 0, stream, db, out);
    hipLaunchKernelGGL(conv_main, dim3(1536), dim3(256), 0, stream, At, XB, bias, dw, out);
}

// Round 4
// 520.136 us; speedup vs baseline: 2.6792x; 1.1214x over previous
//
#include <hip/hip_runtime.h>

#define FF 512
#define LL 12288
#define NJC 1556   // XB chunk count: max jc touched = 1553 (incl. K-roundup + prefetch)
#define NR 128     // XB rows = 16 shifts x 8 batches

typedef _Float16 half8 __attribute__((ext_vector_type(8)));
typedef float    f32x4 __attribute__((ext_vector_type(4)));

// ---------------- Prologue 1: kernel fp32 -> f16, MFMA-A-fragment tiled ----
// At chunk (ft,dc,lane): elem_i = kernel[ft*16 + (lane&15)][dc*32 + (lane>>4)*8 + i]
__global__ __launch_bounds__(256) void build_At(const float* __restrict__ kern,
                                                _Float16* __restrict__ At) {
    int tid  = blockIdx.x * 256 + threadIdx.x;      // 786432 = 512*12288/8
    int lane = tid & 63;
    int rest = tid >> 6;                            // ft*384 + dc
    int dc   = rest % 384;
    int ft   = rest / 384;
    int f    = ft * 16 + (lane & 15);
    int d0   = dc * 32 + (lane >> 4) * 8;
    const float* src = kern + (size_t)f * LL + d0;
    half8 v;
#pragma unroll
    for (int i = 0; i < 8; ++i) v[i] = (_Float16)src[i];
    ((half8*)At)[tid] = v;
}

// ---------------- Prologue 2: B chunk-major layout --------------------------
// XB[jc][r] (16B chunks): r = s*8 + b, s in [0,16). elem_i = x_b[LL-1-(8jc+i)-s]
// (zero when index < 0 -> causal mask, incl. the whole jc >= 1536 pad tail).
__global__ __launch_bounds__(256) void build_XB(const int* __restrict__ ex,
                                                _Float16* __restrict__ XB) {
    int tid = blockIdx.x * 256 + threadIdx.x;       // 199168 = NJC*NR
    if (tid >= NJC * NR) return;
    int r  = tid & 127;
    int jc = tid >> 7;
    int s  = r >> 3, b = r & 7;
    int j0 = jc * 8;
    half8 v;
#pragma unroll
    for (int i = 0; i < 8; ++i) {
        int idx = LL - 1 - (j0 + i) - s;
        float x = 0.f;
        if (idx >= 0) x = (float)ex[b * LL + idx] * 0.5f - 1.0f;
        v[i] = (_Float16)x;
    }
    ((half8*)XB)[tid] = v;
}

// ---------------- Prologue 3: out = dense_b broadcast ----------------------
__global__ __launch_bounds__(256) void init_out(const float* __restrict__ db,
                                                float* __restrict__ out) {
    int tid = blockIdx.x * 256 + threadIdx.x;       // 393216
    out[tid] = db[tid & 3];
}

__device__ __forceinline__ void gl_lds16(const half8* g, half8* l) {
    __builtin_amdgcn_global_load_lds((const __attribute__((address_space(1))) void*)g,
                                     (__attribute__((address_space(3))) void*)l, 16, 0, 0);
}

// ---------------- Main: A via LDS (BK=128 macro-steps), B register-direct --
// Block 128f x 256cols, 4 waves, wave tile 128x64 (8x4 mfma 16x16x32 f16).
// One barrier per 4 K32 sub-steps: 32KB A tile double-buffered (64KB LDS).
// K rounded up to x4; tail MFMAs multiply by XB's zero pad (causal mask).
__global__ __launch_bounds__(256, 2) void conv_main(const _Float16* __restrict__ At,
                                                    const _Float16* __restrict__ XB,
                                                    const float* __restrict__ bias,
                                                    const float* __restrict__ dw,
                                                    float* __restrict__ out) {
    __shared__ half8 Abuf[2][4][8][64];   // 64 KB: [buf][sub][ft][lane]

    int bx    = blockIdx.x;
    int slot  = bx & 7;                // XCD pin: f_blk per XCD pair for L2 reuse
    int f_blk = slot >> 1;             // [0,4)
    int n_blk = 383 - ((bx >> 3) * 2 + (slot & 1));   // largest K first
    int n0 = n_blk << 5;
    int M  = (n_blk + 4) >> 2;         // ceil((n_blk+1)/4) macro (BK=128) steps

    int tid  = threadIdx.x;
    int lane = tid & 63;
    int wid  = tid >> 6;
    int quad = lane >> 4;
    int bb   = lane & 7;
    int nh   = (lane >> 3) & 1;

    // A staging: wave wid stages ft = wid and wid+4; 1KB contiguous per load.
    const half8* Ag  = (const half8*)At;
    const half8* ag0 = Ag + ((size_t)(f_blk * 8 + wid) * 384) * 64 + lane;
    const half8* ag1 = Ag + ((size_t)(f_blk * 8 + wid + 4) * 384) * 64 + lane;

    // B pointers (half8 units): idx = jc*128 + r; per-K32 advance = 4*128 = 512.
    const half8* Bg = (const half8*)XB;
    int jc0 = 1534 - 4 * n_blk + quad - 2 * nh;
    const half8* pB[4];
#pragma unroll
    for (int t = 0; t < 4; ++t) {
        int tt = wid * 4 + t;
        int r  = (15 - tt) * 8 + bb;
        pB[t] = Bg + (size_t)jc0 * 128 + r;
    }

    f32x4 acc[8][4];
#pragma unroll
    for (int r8 = 0; r8 < 8; ++r8)
#pragma unroll
        for (int t = 0; t < 4; ++t) acc[r8][t] = (f32x4){0.f, 0.f, 0.f, 0.f};

    // prologue: stage macro 0 -> buf0, load B(0)
#pragma unroll
    for (int sub = 0; sub < 4; ++sub) {
        gl_lds16(ag0 + (size_t)sub * 64, &Abuf[0][sub][wid][lane]);
        gl_lds16(ag1 + (size_t)sub * 64, &Abuf[0][sub][wid + 4][lane]);
    }
    half8 bcur[4], bnxt[4];
#pragma unroll
    for (int t = 0; t < 4; ++t) bcur[t] = pB[t][0];
    __syncthreads();

    for (int mc = 0; mc < M; ++mc) {
        int buf = mc & 1;
        if (mc + 1 < M) {
            size_t oa = (size_t)(mc + 1) * 256;           // 4 subs x 64 chunks
#pragma unroll
            for (int sub = 0; sub < 4; ++sub) {
                gl_lds16(ag0 + oa + (size_t)sub * 64, &Abuf[buf ^ 1][sub][wid][lane]);
                gl_lds16(ag1 + oa + (size_t)sub * 64, &Abuf[buf ^ 1][sub][wid + 4][lane]);
            }
        }
#pragma unroll
        for (int sub = 0; sub < 4; ++sub) {
            int dc = mc * 4 + sub;
            size_t ob = (size_t)(dc + 1) * 512;
#pragma unroll
            for (int t = 0; t < 4; ++t) bnxt[t] = pB[t][ob];
            half8 a[8];
#pragma unroll
            for (int r8 = 0; r8 < 8; ++r8) a[r8] = Abuf[buf][sub][r8][lane];
#pragma unroll
            for (int r8 = 0; r8 < 8; ++r8)
#pragma unroll
                for (int t = 0; t < 4; ++t)
                    acc[r8][t] = __builtin_amdgcn_mfma_f32_16x16x32_f16(a[r8], bcur[t], acc[r8][t], 0, 0, 0);
#pragma unroll
            for (int t = 0; t < 4; ++t) bcur[t] = bnxt[t];
        }
        __syncthreads();
    }

    // Epilogue: bias + relu + dense over this block's 128 f rows.
    // C/D layout: col = lane&15, row = quad*4 + reg.
    float p[4][4] = {{0.f}};
#pragma unroll
    for (int r8 = 0; r8 < 8; ++r8) {
#pragma unroll
        for (int reg = 0; reg < 4; ++reg) {
            int f = f_blk * 128 + r8 * 16 + quad * 4 + reg;
            float bs = bias[f];
            float4 w = *(const float4*)(dw + (size_t)f * 4);
#pragma unroll
            for (int t = 0; t < 4; ++t) {
                float y = fmaxf(acc[r8][t][reg] + bs, 0.f);
                p[t][0] += y * w.x; p[t][1] += y * w.y;
                p[t][2] += y * w.z; p[t][3] += y * w.w;
            }
        }
    }
#pragma unroll
    for (int t = 0; t < 4; ++t)
#pragma unroll
        for (int c = 0; c < 4; ++c) {
            float v = p[t][c];
            v += __shfl_xor(v, 16, 64);
            v += __shfl_xor(v, 32, 64);
            p[t][c] = v;
        }
    if (quad == 0) {
#pragma unroll
        for (int t = 0; t < 4; ++t) {
            int n = n0 + (wid * 4 + t) + 16 * nh;
            float* o = out + ((size_t)bb * LL + n) * 4;
#pragma unroll
            for (int c = 0; c < 4; ++c) atomicAdd(o + c, p[t][c]);
        }
    }
}

extern "C" void kernel_launch(void* const* d_in, const int* in_sizes, int n_in,
                              void* d_out, int out_size, void* d_ws, size_t ws_size,
                              hipStream_t stream) {
    const int*   ex   = (const int*)d_in[0];
    const float* kern = (const float*)d_in[1];
    const float* bias = (const float*)d_in[2];
    const float* dw   = (const float*)d_in[3];
    const float* db   = (const float*)d_in[4];
    float* out = (float*)d_out;

    _Float16* At = (_Float16*)d_ws;                                   // 12.58 MB
    _Float16* XB = (_Float16*)((char*)d_ws + (size_t)FF * LL * 2);    // +3.05 MB

    hipLaunchKernelGGL(build_At, dim3(3072), dim3(256), 0, stream, kern, At);
    hipLaunchKernelGGL(build_XB, dim3(778),  dim3(256), 0, stream, ex, XB);
    hipLaunchKernelGGL(init_out, dim3(1536), dim3(256), 0, stream, db, out);
    hipLaunchKernelGGL(conv_main, dim3(1536), dim3(256), 0, stream, At, XB, bias, dw, out);
}